// Round 5
// baseline (240.288 us; speedup 1.0000x reference)
//
#include <hip/hip_runtime.h>
#include <hip/hip_bf16.h>
#include <math.h>

#define T0 128
#define BN 256           // B*N = 8*32
#define Ff 128
#define Hh 256
#define NODE0 32768      // BN*T0
#define E0 262144        // NODE0*8
#define T1 64
#define NODE1 16384      // BN*T1
#define E1 131072
#define CAP 48           // per-node in-edge capacity; deg ~ Poisson(8), P(>48) ~ 1e-25

typedef __attribute__((ext_vector_type(8))) short bhalf8;
typedef __attribute__((ext_vector_type(4))) float floatx4;
typedef __attribute__((ext_vector_type(16))) float floatx16;

__device__ __forceinline__ unsigned short f2bf(float x) {
  union { float f; unsigned u; } v; v.f = x;
  unsigned r = v.u + 0x7fff + ((v.u >> 16) & 1);
  return (unsigned short)(r >> 16);
}
__device__ __forceinline__ float bf2f(unsigned short b) {
  union { unsigned u; float f; } v; v.u = ((unsigned)b) << 16;
  return v.f;
}
// update two running maxes from one packed int (2 bf16)
__device__ __forceinline__ void max2(float& mlo, float& mhi, int p) {
  union { unsigned u; float f; } lo, hi;
  lo.u = ((unsigned)p) << 16;
  hi.u = ((unsigned)p) & 0xffff0000u;
  mlo = fmaxf(mlo, lo.f);
  mhi = fmaxf(mhi, hi.f);
}

// async global->LDS, 16B per lane. LDS dest = uniform base + lane*16 (HW rule);
// global src is per-lane. Drained by the implicit vmcnt(0) in __syncthreads().
__device__ __forceinline__ void gload16(const void* g, void* l) {
  __builtin_amdgcn_global_load_lds(
      (const __attribute__((address_space(1))) unsigned int*)g,
      (__attribute__((address_space(3))) unsigned int*)l, 16, 0, 0);
}

// ---------------- fused prep + edge-fill kernel ----------------
__global__ void k_prepfill(const float* __restrict__ data, unsigned short* __restrict__ X0b,
                           const float* __restrict__ W0, unsigned short* __restrict__ Wbot0,
                           unsigned short* __restrict__ Wd0,
                           const float* __restrict__ W1, unsigned short* __restrict__ Wbot1,
                           unsigned short* __restrict__ Wd1,
                           const float* __restrict__ Wc0, unsigned short* __restrict__ Wtb0,
                           const float* __restrict__ Wc1, unsigned short* __restrict__ Wtb1,
                           const int* __restrict__ ei0, const int* __restrict__ ei1,
                           int* __restrict__ cnt0, int* __restrict__ cnt1,
                           int* __restrict__ slot0, int* __restrict__ slot1) {
  int b = blockIdx.x;
  int tid = threadIdx.x;
  if (b < 2048) {
    int idx = b * 256 + tid;          // NODE0*16, 8 elems each
    int c8 = idx & 15;
    int r  = idx >> 4;
    int t  = r & (T0 - 1);
    int bn = r >> 7;
    const float* s = data + ((size_t)t * BN + bn) * Ff + c8 * 8;
    float4 a = *(const float4*)s;
    float4 bb = *(const float4*)(s + 4);
    unsigned short o[8];
    o[0] = f2bf(a.x); o[1] = f2bf(a.y); o[2] = f2bf(a.z); o[3] = f2bf(a.w);
    o[4] = f2bf(bb.x); o[5] = f2bf(bb.y); o[6] = f2bf(bb.z); o[7] = f2bf(bb.w);
    *(int4*)(X0b + ((size_t)(bn * T0 + t) * Ff + c8 * 8)) = *(int4*)o;
  } else if (b < 2176) {
    int idx = (b - 2048) * 256 + tid; // 32768 = 256*128
    int n = idx >> 7, k = idx & 127;
    float top = W0[(size_t)k * 256 + n];
    float bot = W0[(size_t)(128 + k) * 256 + n];
    Wbot0[idx] = f2bf(bot);
    Wd0[idx]   = f2bf(top - bot);
  } else if (b < 2432) {
    int idx = (b - 2176) * 256 + tid; // 65536 = 256*256
    int n = idx >> 8, k = idx & 255;
    float top = W1[(size_t)k * 256 + n];
    float bot = W1[(size_t)(256 + k) * 256 + n];
    Wbot1[idx] = f2bf(bot);
    Wd1[idx]   = f2bf(top - bot);
  } else if (b < 3712) {
    int idx = (b - 2432) * 256 + tid; // 5*65536
    int tap = idx >> 16, o = (idx >> 8) & 255, i = idx & 255;
    Wtb0[idx] = f2bf(Wc0[((size_t)o * 256 + i) * 5 + tap]);
  } else if (b < 4992) {
    int idx = (b - 3712) * 256 + tid;
    int tap = idx >> 16, o = (idx >> 8) & 255, i = idx & 255;
    Wtb1[idx] = f2bf(Wc1[((size_t)o * 256 + i) * 5 + tap]);
  } else {
    int e = (b - 4992) * 256 + tid;   // E0+E1 = 393216 over 1536 blocks
    if (e < E0) {
      int d = ei0[E0 + e];
      int p = atomicAdd(&cnt0[d], 1);
      if (p < CAP) slot0[(size_t)d * CAP + p] = ei0[e];
    } else {
      int e2 = e - E0;
      int d = ei1[E1 + e2];
      int p = atomicAdd(&cnt1[d], 1);
      if (p < CAP) slot1[(size_t)d * CAP + p] = ei1[e2];
    }
  }
}

// ---------------- fused dual-output MFMA GEMM (v4: coalesced epilogue) ----------------
// 128x128 block, 4 waves, 2 row-tiles/wave, swapped-operand MFMA; epilogue via LDS
// restaging to full-line 256B stores (fixed the 1.46x write RMW, verified r4).
__global__ __launch_bounds__(256) void k_gemm2(const unsigned short* __restrict__ A,
                                               const unsigned short* __restrict__ Wbot,
                                               const unsigned short* __restrict__ Wd,
                                               unsigned short* __restrict__ Bm,
                                               unsigned short* __restrict__ P, int K,
                                               const float* __restrict__ bias) {
  __shared__ __align__(16) short S_lds[3 * 128 * 72];  // 55.3 KB
  short* A_lds  = S_lds;
  short* B0_lds = S_lds + 128 * 72;
  short* B1_lds = S_lds + 2 * 128 * 72;
  short* E_lds  = S_lds;            // epilogue tile: 128 rows x 136 shorts
  int tid = threadIdx.x;
  int row0 = blockIdx.x * 128;
  int col0 = blockIdx.y * 128;
  int lane = tid & 63, wv = tid >> 6;
  int m16 = lane & 15, quad = lane >> 4;
  int sr = tid >> 3, sseg = tid & 7;

  floatx4 accB[2][8], accP[2][8];
#pragma unroll
  for (int rt = 0; rt < 2; ++rt)
#pragma unroll
    for (int nt = 0; nt < 8; ++nt) {
      accB[rt][nt] = (floatx4){0.f, 0.f, 0.f, 0.f};
      accP[rt][nt] = (floatx4){0.f, 0.f, 0.f, 0.f};
    }

  for (int kb = 0; kb < K; kb += 64) {
    __syncthreads();
#pragma unroll
    for (int i = 0; i < 4; ++i) {
      int r = sr + i * 32;
      *(int4*)&A_lds[r * 72 + sseg * 8] =
          *(const int4*)(A + (size_t)(row0 + r) * K + kb + sseg * 8);
      *(int4*)&B0_lds[r * 72 + sseg * 8] =
          *(const int4*)(Wbot + (size_t)(col0 + r) * K + kb + sseg * 8);
      *(int4*)&B1_lds[r * 72 + sseg * 8] =
          *(const int4*)(Wd + (size_t)(col0 + r) * K + kb + sseg * 8);
    }
    __syncthreads();
#pragma unroll
    for (int ks = 0; ks < 2; ++ks) {
      bhalf8 a0 = *(const bhalf8*)&A_lds[(wv * 32 + m16) * 72 + ks * 32 + quad * 8];
      bhalf8 a1 = *(const bhalf8*)&A_lds[(wv * 32 + 16 + m16) * 72 + ks * 32 + quad * 8];
#pragma unroll
      for (int nt = 0; nt < 8; ++nt) {
        bhalf8 b0 = *(const bhalf8*)&B0_lds[(nt * 16 + m16) * 72 + ks * 32 + quad * 8];
        accB[0][nt] = __builtin_amdgcn_mfma_f32_16x16x32_bf16(b0, a0, accB[0][nt], 0, 0, 0);
        accB[1][nt] = __builtin_amdgcn_mfma_f32_16x16x32_bf16(b0, a1, accB[1][nt], 0, 0, 0);
        bhalf8 b1 = *(const bhalf8*)&B1_lds[(nt * 16 + m16) * 72 + ks * 32 + quad * 8];
        accP[0][nt] = __builtin_amdgcn_mfma_f32_16x16x32_bf16(b1, a0, accP[0][nt], 0, 0, 0);
        accP[1][nt] = __builtin_amdgcn_mfma_f32_16x16x32_bf16(b1, a1, accP[1][nt], 0, 0, 0);
      }
    }
  }

  const int ESTR = 136;
  __syncthreads();

  // ---- Bm ----
#pragma unroll
  for (int rt = 0; rt < 2; ++rt) {
    int lr = wv * 32 + rt * 16 + m16;
#pragma unroll
    for (int nt = 0; nt < 8; ++nt) {
      ushort4 ob;
      ob.x = f2bf(accB[rt][nt][0]); ob.y = f2bf(accB[rt][nt][1]);
      ob.z = f2bf(accB[rt][nt][2]); ob.w = f2bf(accB[rt][nt][3]);
      *(ushort4*)&E_lds[lr * ESTR + nt * 16 + quad * 4] = ob;
    }
  }
  __syncthreads();
#pragma unroll
  for (int i = 0; i < 8; ++i) {
    int u = tid + i * 256;           // 2048 chunks = 128 rows x 16
    int r = u >> 4, ch = u & 15;
    int4 v = *(const int4*)&E_lds[r * ESTR + ch * 8];
    *(int4*)(Bm + (size_t)(row0 + r) * 256 + col0 + ch * 8) = v;
  }
  __syncthreads();

  // ---- P (+bias) ----
#pragma unroll
  for (int rt = 0; rt < 2; ++rt) {
    int lr = wv * 32 + rt * 16 + m16;
#pragma unroll
    for (int nt = 0; nt < 8; ++nt) {
      int c = col0 + nt * 16 + quad * 4;
      float4 bv = *(const float4*)&bias[c];
      ushort4 op;
      op.x = f2bf(accP[rt][nt][0] + bv.x); op.y = f2bf(accP[rt][nt][1] + bv.y);
      op.z = f2bf(accP[rt][nt][2] + bv.z); op.w = f2bf(accP[rt][nt][3] + bv.w);
      *(ushort4*)&E_lds[lr * ESTR + nt * 16 + quad * 4] = op;
    }
  }
  __syncthreads();
#pragma unroll
  for (int i = 0; i < 8; ++i) {
    int u = tid + i * 256;
    int r = u >> 4, ch = u & 15;
    int4 v = *(const int4*)&E_lds[r * ESTR + ch * 8];
    *(int4*)(P + (size_t)(row0 + r) * 256 + col0 + ch * 8) = v;
  }
}

// ---------------- segment max + fused relu epilogue (v2, kept) ----------------
__global__ __launch_bounds__(256) void k_maxg2(const unsigned short* __restrict__ Bm,
                                               const int* __restrict__ cnt,
                                               const int* __restrict__ slot,
                                               const unsigned short* __restrict__ P,
                                               unsigned short* __restrict__ X1) {
  int node = blockIdx.x * 4 + (threadIdx.x >> 6);
  int lane = threadIdx.x & 63;
  int half = lane >> 5, c8 = lane & 31;
  int n = cnt[node];
  if (n > CAP) n = CAP;
  const int* sl = slot + (size_t)node * CAP;
  float m[8];
#pragma unroll
  for (int e = 0; e < 8; ++e) m[e] = -INFINITY;
  for (int i = 0; i < n; i += 8) {
    int s[4];
#pragma unroll
    for (int j = 0; j < 4; ++j) {
      int idx = i + 2 * j + half;
      s[j] = sl[(idx < n) ? idx : (n - 1)];
    }
    int4 v[4];
#pragma unroll
    for (int j = 0; j < 4; ++j)
      v[j] = *(const int4*)(Bm + (size_t)s[j] * 256 + c8 * 8);
#pragma unroll
    for (int j = 0; j < 4; ++j) {
      max2(m[0], m[1], v[j].x);
      max2(m[2], m[3], v[j].y);
      max2(m[4], m[5], v[j].z);
      max2(m[6], m[7], v[j].w);
    }
  }
#pragma unroll
  for (int e = 0; e < 8; ++e) m[e] = fmaxf(m[e], __shfl_xor(m[e], 32));
  if (half == 0) {
    int4 p = *(const int4*)(P + (size_t)node * 256 + c8 * 8);
    int4 o;
    unsigned short r0, r1;
    r0 = f2bf(fmaxf(bf2f((unsigned short)(p.x & 0xffff)) + m[0], 0.f));
    r1 = f2bf(fmaxf(bf2f((unsigned short)((unsigned)p.x >> 16)) + m[1], 0.f));
    o.x = (int)r0 | ((int)r1 << 16);
    r0 = f2bf(fmaxf(bf2f((unsigned short)(p.y & 0xffff)) + m[2], 0.f));
    r1 = f2bf(fmaxf(bf2f((unsigned short)((unsigned)p.y >> 16)) + m[3], 0.f));
    o.y = (int)r0 | ((int)r1 << 16);
    r0 = f2bf(fmaxf(bf2f((unsigned short)(p.z & 0xffff)) + m[4], 0.f));
    r1 = f2bf(fmaxf(bf2f((unsigned short)((unsigned)p.z >> 16)) + m[5], 0.f));
    o.z = (int)r0 | ((int)r1 << 16);
    r0 = f2bf(fmaxf(bf2f((unsigned short)(p.w & 0xffff)) + m[6], 0.f));
    r1 = f2bf(fmaxf(bf2f((unsigned short)((unsigned)p.w >> 16)) + m[7], 0.f));
    o.w = (int)r0 | ((int)r1 << 16);
    *(int4*)(X1 + (size_t)node * 256 + c8 * 8) = o;
  }
}

// ---------------- MFMA temporal conv (v5: global_load_lds + LDS double-buffer) ----------------
// Block 128 rows x 128 cols, 4 waves (2 row-halves x 2 col-parts).
// Per buffer: A = 2 halo windows x 80 rows (68 used, 80 for 16-row DMA granularity),
// B = 5 taps x 128 cols; rows are 64B (32 shorts), unpadded/linear so
// global_load_lds can write them (uniform LDS base + lane*16B).
// Bank swizzle (rule: both-sides-or-neither): content LDS[rho][c] = G[rho][c ^ s(rho)],
// s(rho) = (rho>>1)&3 -> staging fetches source chunk (lane&3)^s(rho); ds_read applies
// the same XOR. 32 consecutive rows/read spread over 8 bank-quads (~4-way, same as
// the old padded layout) while the DMA write side is stride-1 conflict-free.
// Pipeline: issue DMA for chunk t+1, compute chunk t from the other buffer,
// __syncthreads() (implicit vmcnt(0) drains own DMAs; barrier orders buffers).
// One barrier per chunk (was 2), zero ds_writes, zero staging VGPRs.
// Out-of-range halo rows: source redirected to a zeroed 256B pad.
template <int TRows, bool OUT_F32>
__global__ __launch_bounds__(256) void k_conv32(const unsigned short* __restrict__ X,
                                                const unsigned short* __restrict__ Wtb,
                                                const float* __restrict__ bc,
                                                const unsigned short* __restrict__ zpad,
                                                void* __restrict__ Yout) {
  __shared__ __align__(16) short LDS[2][800 * 32];  // (160 A-rows + 640 B-rows) x 64B x 2buf = 100KB
  int tid = threadIdx.x;
  int row0 = blockIdx.x * 128;
  int col0 = blockIdx.y * 128;
  int lane = tid & 63, wv = tid >> 6;
  int l31 = lane & 31, khalf = lane >> 5;
  int h = wv & 1, cpart = wv >> 1;
  int lq = lane >> 2, lc = lane & 3;   // lane's dest row-offset (0..15) and 16B chunk (0..3)

  floatx16 acc[2][2];
#pragma unroll
  for (int rt = 0; rt < 2; ++rt)
#pragma unroll
    for (int ct = 0; ct < 2; ++ct)
#pragma unroll
      for (int r = 0; r < 16; ++r) acc[rt][ct][r] = 0.f;

  // stage one K-chunk (32 elems = 64B/row) into LDS[buf]: 50 DMA instrs split over 4 waves
  auto stage = [&](int buf, int kb) {
    for (int i = wv; i < 50; i += 4) {
      const unsigned short* src;
      int rho0;
      if (i < 10) {                       // A: window s (5 instrs each of 16 rows)
        int s = (i >= 5) ? 1 : 0;
        int j = i - s * 5;
        rho0 = s * 80 + j * 16;
        int r = j * 16 + lq;              // 0..79 within window
        int rho = rho0 + lq;
        int cs = lc ^ ((rho >> 1) & 3);
        int gr = row0 + s * 64 - 2 + r;
        int lo = (row0 + s * 64) & ~(TRows - 1);
        bool ok = (r < 68) && (gr >= lo) && (gr < lo + TRows);
        src = ok ? (X + (size_t)gr * 256 + kb + cs * 8) : (zpad + lc * 8);
      } else {                            // B: 40 instrs over 640 rows (tap*128 + col)
        int j = i - 10;
        rho0 = 160 + j * 16;
        int v = j * 16 + lq;
        int rho = rho0 + lq;
        int cs = lc ^ ((rho >> 1) & 3);
        int tap = v >> 7, col = v & 127;
        src = Wtb + (size_t)tap * 65536 + (size_t)(col0 + col) * 256 + kb + cs * 8;
      }
      gload16(src, &LDS[buf][rho0 * 32]);
    }
  };

  stage(0, 0);
  __syncthreads();
  int cur = 0;
  for (int t = 0; t < 8; ++t) {
    if (t < 7) stage(cur ^ 1, (t + 1) * 32);
#pragma unroll
    for (int tap = 0; tap < 5; ++tap) {
#pragma unroll
      for (int ks = 0; ks < 2; ++ks) {
        int c = ks * 2 + khalf;
        bhalf8 a[2];
#pragma unroll
        for (int rt = 0; rt < 2; ++rt) {
          int rho = h * 80 + rt * 32 + l31 + tap;
          a[rt] = *(const bhalf8*)&LDS[cur][rho * 32 + ((c ^ ((rho >> 1) & 3)) * 8)];
        }
#pragma unroll
        for (int ct = 0; ct < 2; ++ct) {
          int rho = 160 + tap * 128 + cpart * 64 + ct * 32 + l31;
          bhalf8 b = *(const bhalf8*)&LDS[cur][rho * 32 + ((c ^ ((rho >> 1) & 3)) * 8)];
#pragma unroll
          for (int rt = 0; rt < 2; ++rt)
            acc[rt][ct] = __builtin_amdgcn_mfma_f32_32x32x16_bf16(a[rt], b, acc[rt][ct], 0, 0, 0);
        }
      }
    }
    __syncthreads();
    cur ^= 1;
  }

#pragma unroll
  for (int rt = 0; rt < 2; ++rt) {
#pragma unroll
    for (int ct = 0; ct < 2; ++ct) {
      int c = col0 + cpart * 64 + ct * 32 + l31;
      float bv = bc[c];
#pragma unroll
      for (int r = 0; r < 16; r += 2) {
        int rowg = row0 + h * 64 + rt * 32 + 4 * khalf + 8 * (r >> 2) + (r & 3);
        float y0 = fmaxf(acc[rt][ct][r] + bv, 0.f);
        float y1 = fmaxf(acc[rt][ct][r + 1] + bv, 0.f);
        float p = fmaxf(y0, y1);
        int o = rowg >> 1;
        if (OUT_F32) ((float*)Yout)[(size_t)o * 256 + c] = p;
        else ((unsigned short*)Yout)[(size_t)o * 256 + c] = f2bf(p);
      }
    }
  }
}

extern "C" void kernel_launch(void* const* d_in, const int* in_sizes, int n_in,
                              void* d_out, int out_size, void* d_ws, size_t ws_size,
                              hipStream_t stream) {
  const float* data = (const float*)d_in[0];
  const int* ei0 = (const int*)d_in[2];
  const int* ei1 = (const int*)d_in[3];
  const float* W0  = (const float*)d_in[4];
  const float* b0  = (const float*)d_in[5];
  const float* Wc0 = (const float*)d_in[6];
  const float* bc0 = (const float*)d_in[7];
  const float* W1  = (const float*)d_in[8];
  const float* b1  = (const float*)d_in[9];
  const float* Wc1 = (const float*)d_in[10];
  const float* bc1 = (const float*)d_in[11];
  float* out = (float*)d_out;

  char* base = (char*)d_ws;
  size_t off = 0;
  auto alloc = [&](size_t bytes) { void* p = base + off; off += (bytes + 255) & ~(size_t)255; return p; };
  unsigned short* X0b   = (unsigned short*)alloc((size_t)NODE0 * Ff * 2);
  unsigned short* Bm    = (unsigned short*)alloc((size_t)NODE0 * Hh * 2);
  unsigned short* P     = (unsigned short*)alloc((size_t)NODE0 * Hh * 2);
  unsigned short* X1b   = (unsigned short*)alloc((size_t)NODE0 * Hh * 2);
  unsigned short* Y0b   = (unsigned short*)alloc((size_t)NODE1 * Hh * 2);
  unsigned short* Wbot0 = (unsigned short*)alloc(256 * 128 * 2);
  unsigned short* Wd0   = (unsigned short*)alloc(256 * 128 * 2);
  unsigned short* Wbot1 = (unsigned short*)alloc(256 * 256 * 2);
  unsigned short* Wd1   = (unsigned short*)alloc(256 * 256 * 2);
  unsigned short* Wtb0  = (unsigned short*)alloc(5 * 65536 * 2);
  unsigned short* Wtb1  = (unsigned short*)alloc(5 * 65536 * 2);
  int* cnt0  = (int*)alloc(NODE0 * 4);      // cnt0+cnt1+zpad adjacent: one memset
  int* cnt1  = (int*)alloc(NODE1 * 4);
  unsigned short* zpad = (unsigned short*)alloc(256);
  int* slot0 = (int*)alloc((size_t)NODE0 * CAP * 4);
  int* slot1 = (int*)alloc((size_t)NODE1 * CAP * 4);

  hipMemsetAsync(cnt0, 0, (NODE0 + NODE1) * sizeof(int) + 256, stream);

  k_prepfill<<<6528, 256, 0, stream>>>(data, X0b, W0, Wbot0, Wd0, W1, Wbot1, Wd1,
                                       Wc0, Wtb0, Wc1, Wtb1,
                                       ei0, ei1, cnt0, cnt1, slot0, slot1);

  // ---- layer 0 ----
  k_gemm2<<<dim3(NODE0 / 128, 2), 256, 0, stream>>>(X0b, Wbot0, Wd0, Bm, P, 128, b0);
  k_maxg2<<<NODE0 / 4, 256, 0, stream>>>(Bm, cnt0, slot0, P, X1b);
  k_conv32<128, false><<<dim3(NODE0 / 128, 2), 256, 0, stream>>>(X1b, Wtb0, bc0, zpad, Y0b);

  // ---- layer 1 ----
  k_gemm2<<<dim3(NODE1 / 128, 2), 256, 0, stream>>>(Y0b, Wbot1, Wd1, Bm, P, 256, b1);
  k_maxg2<<<NODE1 / 4, 256, 0, stream>>>(Bm, cnt1, slot1, P, X1b);
  k_conv32<64, true><<<dim3(NODE1 / 128, 2), 256, 0, stream>>>(X1b, Wtb1, bc1, zpad, out);
}

// Round 6
// 231.575 us; speedup vs baseline: 1.0376x; 1.0376x over previous
//
#include <hip/hip_runtime.h>
#include <hip/hip_bf16.h>
#include <math.h>

#define T0 128
#define BN 256           // B*N = 8*32
#define Ff 128
#define Hh 256
#define NODE0 32768      // BN*T0
#define E0 262144        // NODE0*8
#define T1 64
#define NODE1 16384      // BN*T1
#define E1 131072
#define CAP 48           // per-node in-edge capacity; deg ~ Poisson(8), P(>48) ~ 1e-25

typedef __attribute__((ext_vector_type(8))) short bhalf8;
typedef __attribute__((ext_vector_type(4))) float floatx4;
typedef __attribute__((ext_vector_type(16))) float floatx16;

__device__ __forceinline__ unsigned short f2bf(float x) {
  union { float f; unsigned u; } v; v.f = x;
  unsigned r = v.u + 0x7fff + ((v.u >> 16) & 1);
  return (unsigned short)(r >> 16);
}
__device__ __forceinline__ float bf2f(unsigned short b) {
  union { unsigned u; float f; } v; v.u = ((unsigned)b) << 16;
  return v.f;
}
// update two running maxes from one packed int (2 bf16)
__device__ __forceinline__ void max2(float& mlo, float& mhi, int p) {
  union { unsigned u; float f; } lo, hi;
  lo.u = ((unsigned)p) << 16;
  hi.u = ((unsigned)p) & 0xffff0000u;
  mlo = fmaxf(mlo, lo.f);
  mhi = fmaxf(mhi, hi.f);
}

// ---------------- fused prep + edge-fill kernel ----------------
__global__ void k_prepfill(const float* __restrict__ data, unsigned short* __restrict__ X0b,
                           const float* __restrict__ W0, unsigned short* __restrict__ Wbot0,
                           unsigned short* __restrict__ Wd0,
                           const float* __restrict__ W1, unsigned short* __restrict__ Wbot1,
                           unsigned short* __restrict__ Wd1,
                           const float* __restrict__ Wc0, unsigned short* __restrict__ Wtb0,
                           const float* __restrict__ Wc1, unsigned short* __restrict__ Wtb1,
                           const int* __restrict__ ei0, const int* __restrict__ ei1,
                           int* __restrict__ cnt0, int* __restrict__ cnt1,
                           int* __restrict__ slot0, int* __restrict__ slot1) {
  int b = blockIdx.x;
  int tid = threadIdx.x;
  if (b < 2048) {
    int idx = b * 256 + tid;          // NODE0*16, 8 elems each
    int c8 = idx & 15;
    int r  = idx >> 4;
    int t  = r & (T0 - 1);
    int bn = r >> 7;
    const float* s = data + ((size_t)t * BN + bn) * Ff + c8 * 8;
    float4 a = *(const float4*)s;
    float4 bb = *(const float4*)(s + 4);
    unsigned short o[8];
    o[0] = f2bf(a.x); o[1] = f2bf(a.y); o[2] = f2bf(a.z); o[3] = f2bf(a.w);
    o[4] = f2bf(bb.x); o[5] = f2bf(bb.y); o[6] = f2bf(bb.z); o[7] = f2bf(bb.w);
    *(int4*)(X0b + ((size_t)(bn * T0 + t) * Ff + c8 * 8)) = *(int4*)o;
  } else if (b < 2176) {
    int idx = (b - 2048) * 256 + tid; // 32768 = 256*128
    int n = idx >> 7, k = idx & 127;
    float top = W0[(size_t)k * 256 + n];
    float bot = W0[(size_t)(128 + k) * 256 + n];
    Wbot0[idx] = f2bf(bot);
    Wd0[idx]   = f2bf(top - bot);
  } else if (b < 2432) {
    int idx = (b - 2176) * 256 + tid; // 65536 = 256*256
    int n = idx >> 8, k = idx & 255;
    float top = W1[(size_t)k * 256 + n];
    float bot = W1[(size_t)(256 + k) * 256 + n];
    Wbot1[idx] = f2bf(bot);
    Wd1[idx]   = f2bf(top - bot);
  } else if (b < 3712) {
    int idx = (b - 2432) * 256 + tid; // 5*65536
    int tap = idx >> 16, o = (idx >> 8) & 255, i = idx & 255;
    Wtb0[idx] = f2bf(Wc0[((size_t)o * 256 + i) * 5 + tap]);
  } else if (b < 4992) {
    int idx = (b - 3712) * 256 + tid;
    int tap = idx >> 16, o = (idx >> 8) & 255, i = idx & 255;
    Wtb1[idx] = f2bf(Wc1[((size_t)o * 256 + i) * 5 + tap]);
  } else {
    int e = (b - 4992) * 256 + tid;   // E0+E1 = 393216 over 1536 blocks
    if (e < E0) {
      int d = ei0[E0 + e];
      int p = atomicAdd(&cnt0[d], 1);
      if (p < CAP) slot0[(size_t)d * CAP + p] = ei0[e];
    } else {
      int e2 = e - E0;
      int d = ei1[E1 + e2];
      int p = atomicAdd(&cnt1[d], 1);
      if (p < CAP) slot1[(size_t)d * CAP + p] = ei1[e2];
    }
  }
}

// ---------------- fused dual-output MFMA GEMM (v5: two-pass, 4 blocks/CU) ----------------
// 128x128 block, 4 waves, 2 row-tiles/wave, swapped-operand MFMA, coalesced LDS
// epilogue (r4-verified). NEW: Bm and P computed in two sequential passes sharing
// ONE A+B staging buffer: LDS 55->36.8KB and live acc 128->64 VGPR, so
// __launch_bounds__(256,4) gives 4 blocks/CU (was 2). The gemm is store-tail
// bound (~128KB/block streamed at block end); 4 desynchronized blocks/CU
// overlap one block's store tail with others' k-loops. Cost: A staged twice.
__global__ __launch_bounds__(256, 4) void k_gemm2(const unsigned short* __restrict__ A,
                                                  const unsigned short* __restrict__ Wbot,
                                                  const unsigned short* __restrict__ Wd,
                                                  unsigned short* __restrict__ Bm,
                                                  unsigned short* __restrict__ P, int K,
                                                  const float* __restrict__ bias) {
  __shared__ __align__(16) short S_lds[2 * 128 * 72];  // 36.8 KB
  short* A_lds = S_lds;
  short* B_lds = S_lds + 128 * 72;
  short* E_lds = S_lds;            // epilogue tile: 128 rows x 136 shorts (17408 <= 18432)
  const int ESTR = 136;
  int tid = threadIdx.x;
  int row0 = blockIdx.x * 128;
  int col0 = blockIdx.y * 128;
  int lane = tid & 63, wv = tid >> 6;
  int m16 = lane & 15, quad = lane >> 4;
  int sr = tid >> 3, sseg = tid & 7;

#pragma unroll
  for (int pass = 0; pass < 2; ++pass) {
    const unsigned short* Bsrc = pass ? Wd : Wbot;
    floatx4 acc[2][8];
#pragma unroll
    for (int rt = 0; rt < 2; ++rt)
#pragma unroll
      for (int nt = 0; nt < 8; ++nt) acc[rt][nt] = (floatx4){0.f, 0.f, 0.f, 0.f};

    for (int kb = 0; kb < K; kb += 64) {
      __syncthreads();
#pragma unroll
      for (int i = 0; i < 4; ++i) {
        int r = sr + i * 32;
        *(int4*)&A_lds[r * 72 + sseg * 8] =
            *(const int4*)(A + (size_t)(row0 + r) * K + kb + sseg * 8);
        *(int4*)&B_lds[r * 72 + sseg * 8] =
            *(const int4*)(Bsrc + (size_t)(col0 + r) * K + kb + sseg * 8);
      }
      __syncthreads();
#pragma unroll
      for (int ks = 0; ks < 2; ++ks) {
        bhalf8 a0 = *(const bhalf8*)&A_lds[(wv * 32 + m16) * 72 + ks * 32 + quad * 8];
        bhalf8 a1 = *(const bhalf8*)&A_lds[(wv * 32 + 16 + m16) * 72 + ks * 32 + quad * 8];
#pragma unroll
        for (int nt = 0; nt < 8; ++nt) {
          bhalf8 b = *(const bhalf8*)&B_lds[(nt * 16 + m16) * 72 + ks * 32 + quad * 8];
          acc[0][nt] = __builtin_amdgcn_mfma_f32_16x16x32_bf16(b, a0, acc[0][nt], 0, 0, 0);
          acc[1][nt] = __builtin_amdgcn_mfma_f32_16x16x32_bf16(b, a1, acc[1][nt], 0, 0, 0);
        }
      }
    }

    // swapped C/D layout: lane holds node row = row0+wv*32+rt*16+m16,
    // channels col0 + nt*16 + quad*4 + r.
    __syncthreads();   // k-loop LDS reads done before E_lds overwrite
#pragma unroll
    for (int rt = 0; rt < 2; ++rt) {
      int lr = wv * 32 + rt * 16 + m16;
#pragma unroll
      for (int nt = 0; nt < 8; ++nt) {
        int c = col0 + nt * 16 + quad * 4;
        floatx4 v = acc[rt][nt];
        if (pass) {
          float4 bv = *(const float4*)&bias[c];
          v[0] += bv.x; v[1] += bv.y; v[2] += bv.z; v[3] += bv.w;
        }
        ushort4 o;
        o.x = f2bf(v[0]); o.y = f2bf(v[1]); o.z = f2bf(v[2]); o.w = f2bf(v[3]);
        *(ushort4*)&E_lds[lr * ESTR + nt * 16 + quad * 4] = o;
      }
    }
    __syncthreads();
    unsigned short* Out = pass ? P : Bm;
#pragma unroll
    for (int i = 0; i < 8; ++i) {
      int u = tid + i * 256;           // 2048 chunks = 128 rows x 16
      int r = u >> 4, ch = u & 15;
      int4 v = *(const int4*)&E_lds[r * ESTR + ch * 8];
      *(int4*)(Out + (size_t)(row0 + r) * 256 + col0 + ch * 8) = v;
    }
    // next pass's first k-loop barrier orders E_lds reads vs restaging
  }
}

// ---------------- segment max + fused relu epilogue (v2, kept) ----------------
__global__ __launch_bounds__(256) void k_maxg2(const unsigned short* __restrict__ Bm,
                                               const int* __restrict__ cnt,
                                               const int* __restrict__ slot,
                                               const unsigned short* __restrict__ P,
                                               unsigned short* __restrict__ X1) {
  int node = blockIdx.x * 4 + (threadIdx.x >> 6);
  int lane = threadIdx.x & 63;
  int half = lane >> 5, c8 = lane & 31;
  int n = cnt[node];
  if (n > CAP) n = CAP;
  const int* sl = slot + (size_t)node * CAP;
  float m[8];
#pragma unroll
  for (int e = 0; e < 8; ++e) m[e] = -INFINITY;
  for (int i = 0; i < n; i += 8) {
    int s[4];
#pragma unroll
    for (int j = 0; j < 4; ++j) {
      int idx = i + 2 * j + half;
      s[j] = sl[(idx < n) ? idx : (n - 1)];
    }
    int4 v[4];
#pragma unroll
    for (int j = 0; j < 4; ++j)
      v[j] = *(const int4*)(Bm + (size_t)s[j] * 256 + c8 * 8);
#pragma unroll
    for (int j = 0; j < 4; ++j) {
      max2(m[0], m[1], v[j].x);
      max2(m[2], m[3], v[j].y);
      max2(m[4], m[5], v[j].z);
      max2(m[6], m[7], v[j].w);
    }
  }
#pragma unroll
  for (int e = 0; e < 8; ++e) m[e] = fmaxf(m[e], __shfl_xor(m[e], 32));
  if (half == 0) {
    int4 p = *(const int4*)(P + (size_t)node * 256 + c8 * 8);
    int4 o;
    unsigned short r0, r1;
    r0 = f2bf(fmaxf(bf2f((unsigned short)(p.x & 0xffff)) + m[0], 0.f));
    r1 = f2bf(fmaxf(bf2f((unsigned short)((unsigned)p.x >> 16)) + m[1], 0.f));
    o.x = (int)r0 | ((int)r1 << 16);
    r0 = f2bf(fmaxf(bf2f((unsigned short)(p.y & 0xffff)) + m[2], 0.f));
    r1 = f2bf(fmaxf(bf2f((unsigned short)((unsigned)p.y >> 16)) + m[3], 0.f));
    o.y = (int)r0 | ((int)r1 << 16);
    r0 = f2bf(fmaxf(bf2f((unsigned short)(p.z & 0xffff)) + m[4], 0.f));
    r1 = f2bf(fmaxf(bf2f((unsigned short)((unsigned)p.z >> 16)) + m[5], 0.f));
    o.z = (int)r0 | ((int)r1 << 16);
    r0 = f2bf(fmaxf(bf2f((unsigned short)(p.w & 0xffff)) + m[6], 0.f));
    r1 = f2bf(fmaxf(bf2f((unsigned short)((unsigned)p.w >> 16)) + m[7], 0.f));
    o.w = (int)r0 | ((int)r1 << 16);
    *(int4*)(X1 + (size_t)node * 256 + c8 * 8) = o;
  }
}

// ---------------- MFMA temporal conv (r4 direct staging, REVERTED from v5) ----------------
// v5's DMA double-buffer lost: 100KB LDS -> 1 block/CU exposed every barrier
// (50.9us, MfmaUtil 16%). This 62KB pad-40 version runs 2 blocks/CU; staging
// of one block hides under compute of the other.
template <int TRows, int NT, bool OUT_F32>
__global__ __launch_bounds__(256) void k_conv32(const unsigned short* __restrict__ X,
                                                const unsigned short* __restrict__ Wtb,
                                                const float* __restrict__ bc,
                                                void* __restrict__ Yout) {
  const int CB = NT * 64;                        // block cols
  __shared__ __align__(16) short A_lds[2 * 68 * 40];   // [win][row 0..67][k32 + pad8]
  __shared__ __align__(16) short B_lds[5 * CB * 40];   // [tap*CB + col][k32 + pad8]
  int tid = threadIdx.x;
  int row0 = blockIdx.x * 128;
  int col0 = blockIdx.y * CB;
  int lane = tid & 63, wv = tid >> 6;
  int l31 = lane & 31, khalf = lane >> 5;
  int h = wv & 1, cpart = wv >> 1;

  floatx16 acc[2][NT];
#pragma unroll
  for (int rt = 0; rt < 2; ++rt)
#pragma unroll
    for (int ct = 0; ct < NT; ++ct)
#pragma unroll
      for (int r = 0; r < 16; ++r) acc[rt][ct][r] = 0.f;

  for (int kb = 0; kb < 256; kb += 32) {
    __syncthreads();
    // stage A: two 68-row halo windows (rows base-2 .. base+66), zero outside bn
    for (int u = tid; u < 544; u += 256) {
      int s = (u >= 272) ? 1 : 0;
      int v = u - s * 272;
      int rr = v >> 2, seg = v & 3;
      int base = row0 + s * 64;
      int lo = base & ~(TRows - 1);
      int gr = base + rr - 2;
      int4 val = {0, 0, 0, 0};
      if (gr >= lo && gr < lo + TRows)
        val = *(const int4*)(X + (size_t)gr * 256 + kb + seg * 8);
      *(int4*)&A_lds[(s * 68 + rr) * 40 + seg * 8] = val;
    }
    // stage B: 5 taps x CB cols x 32 k
#pragma unroll
    for (int i = 0; i < 5 * NT; ++i) {
      int u = tid + i * 256;            // 5*CB rows x 4 segs
      int r = u >> 2, seg = u & 3;      // r = tap*CB + col
      int tap = r / CB, col = r % CB;
      *(int4*)&B_lds[r * 40 + seg * 8] =
          *(const int4*)(Wtb + (size_t)tap * 65536 + (size_t)(col0 + col) * 256 + kb + seg * 8);
    }
    __syncthreads();
#pragma unroll
    for (int tap = 0; tap < 5; ++tap) {
#pragma unroll
      for (int ks = 0; ks < 2; ++ks) {
        int ko = ks * 16 + khalf * 8;
        bhalf8 a[2];
#pragma unroll
        for (int rt = 0; rt < 2; ++rt)
          a[rt] = *(const bhalf8*)&A_lds[(h * 68 + rt * 32 + l31 + tap) * 40 + ko];
#pragma unroll
        for (int ct = 0; ct < NT; ++ct) {
          bhalf8 b = *(const bhalf8*)&B_lds[(tap * CB + cpart * NT * 32 + ct * 32 + l31) * 40 + ko];
#pragma unroll
          for (int rt = 0; rt < 2; ++rt)
            acc[rt][ct] = __builtin_amdgcn_mfma_f32_32x32x16_bf16(a[rt], b, acc[rt][ct], 0, 0, 0);
        }
      }
    }
  }

#pragma unroll
  for (int rt = 0; rt < 2; ++rt) {
#pragma unroll
    for (int ct = 0; ct < NT; ++ct) {
      int c = col0 + cpart * NT * 32 + ct * 32 + l31;
      float bv = bc[c];
#pragma unroll
      for (int r = 0; r < 16; r += 2) {
        int rowg = row0 + h * 64 + rt * 32 + 4 * khalf + 8 * (r >> 2) + (r & 3);
        float y0 = fmaxf(acc[rt][ct][r] + bv, 0.f);
        float y1 = fmaxf(acc[rt][ct][r + 1] + bv, 0.f);
        float p = fmaxf(y0, y1);
        int o = rowg >> 1;
        if (OUT_F32) ((float*)Yout)[(size_t)o * 256 + c] = p;
        else ((unsigned short*)Yout)[(size_t)o * 256 + c] = f2bf(p);
      }
    }
  }
}

extern "C" void kernel_launch(void* const* d_in, const int* in_sizes, int n_in,
                              void* d_out, int out_size, void* d_ws, size_t ws_size,
                              hipStream_t stream) {
  const float* data = (const float*)d_in[0];
  const int* ei0 = (const int*)d_in[2];
  const int* ei1 = (const int*)d_in[3];
  const float* W0  = (const float*)d_in[4];
  const float* b0  = (const float*)d_in[5];
  const float* Wc0 = (const float*)d_in[6];
  const float* bc0 = (const float*)d_in[7];
  const float* W1  = (const float*)d_in[8];
  const float* b1  = (const float*)d_in[9];
  const float* Wc1 = (const float*)d_in[10];
  const float* bc1 = (const float*)d_in[11];
  float* out = (float*)d_out;

  char* base = (char*)d_ws;
  size_t off = 0;
  auto alloc = [&](size_t bytes) { void* p = base + off; off += (bytes + 255) & ~(size_t)255; return p; };
  unsigned short* X0b   = (unsigned short*)alloc((size_t)NODE0 * Ff * 2);
  unsigned short* Bm    = (unsigned short*)alloc((size_t)NODE0 * Hh * 2);
  unsigned short* P     = (unsigned short*)alloc((size_t)NODE0 * Hh * 2);
  unsigned short* X1b   = (unsigned short*)alloc((size_t)NODE0 * Hh * 2);
  unsigned short* Y0b   = (unsigned short*)alloc((size_t)NODE1 * Hh * 2);
  unsigned short* Wbot0 = (unsigned short*)alloc(256 * 128 * 2);
  unsigned short* Wd0   = (unsigned short*)alloc(256 * 128 * 2);
  unsigned short* Wbot1 = (unsigned short*)alloc(256 * 256 * 2);
  unsigned short* Wd1   = (unsigned short*)alloc(256 * 256 * 2);
  unsigned short* Wtb0  = (unsigned short*)alloc(5 * 65536 * 2);
  unsigned short* Wtb1  = (unsigned short*)alloc(5 * 65536 * 2);
  int* cnt0  = (int*)alloc(NODE0 * 4);      // cnt0+cnt1 adjacent: one memset
  int* cnt1  = (int*)alloc(NODE1 * 4);
  int* slot0 = (int*)alloc((size_t)NODE0 * CAP * 4);
  int* slot1 = (int*)alloc((size_t)NODE1 * CAP * 4);

  hipMemsetAsync(cnt0, 0, (NODE0 + NODE1) * sizeof(int), stream);

  k_prepfill<<<6528, 256, 0, stream>>>(data, X0b, W0, Wbot0, Wd0, W1, Wbot1, Wd1,
                                       Wc0, Wtb0, Wc1, Wtb1,
                                       ei0, ei1, cnt0, cnt1, slot0, slot1);

  // ---- layer 0 ----
  k_gemm2<<<dim3(NODE0 / 128, 2), 256, 0, stream>>>(X0b, Wbot0, Wd0, Bm, P, 128, b0);
  k_maxg2<<<NODE0 / 4, 256, 0, stream>>>(Bm, cnt0, slot0, P, X1b);
  k_conv32<128, 2, false><<<dim3(NODE0 / 128, 2), 256, 0, stream>>>(X1b, Wtb0, bc0, Y0b);

  // ---- layer 1 ----
  k_gemm2<<<dim3(NODE1 / 128, 2), 256, 0, stream>>>(Y0b, Wbot1, Wd1, Bm, P, 256, b1);
  k_maxg2<<<NODE1 / 4, 256, 0, stream>>>(Bm, cnt1, slot1, P, X1b);
  k_conv32<64, 2, true><<<dim3(NODE1 / 128, 2), 256, 0, stream>>>(X1b, Wtb1, bc1, out);
}

// Round 7
// 227.181 us; speedup vs baseline: 1.0577x; 1.0193x over previous
//
#include <hip/hip_runtime.h>
#include <hip/hip_bf16.h>
#include <math.h>

#define T0 128
#define BN 256           // B*N = 8*32
#define Ff 128
#define Hh 256
#define NODE0 32768      // BN*T0
#define E0 262144        // NODE0*8
#define T1 64
#define NODE1 16384      // BN*T1
#define E1 131072
#define CAP 48           // per-node in-edge capacity; deg ~ Poisson(8), P(>48) ~ 1e-25

typedef __attribute__((ext_vector_type(8))) short bhalf8;
typedef __attribute__((ext_vector_type(4))) float floatx4;
typedef __attribute__((ext_vector_type(16))) float floatx16;

__device__ __forceinline__ unsigned short f2bf(float x) {
  union { float f; unsigned u; } v; v.f = x;
  unsigned r = v.u + 0x7fff + ((v.u >> 16) & 1);
  return (unsigned short)(r >> 16);
}
__device__ __forceinline__ float bf2f(unsigned short b) {
  union { unsigned u; float f; } v; v.u = ((unsigned)b) << 16;
  return v.f;
}
// update two running maxes from one packed int (2 bf16)
__device__ __forceinline__ void max2(float& mlo, float& mhi, int p) {
  union { unsigned u; float f; } lo, hi;
  lo.u = ((unsigned)p) << 16;
  hi.u = ((unsigned)p) & 0xffff0000u;
  mlo = fmaxf(mlo, lo.f);
  mhi = fmaxf(mhi, hi.f);
}

// ---------------- fused prep + edge-fill kernel ----------------
__global__ void k_prepfill(const float* __restrict__ data, unsigned short* __restrict__ X0b,
                           const float* __restrict__ W0, unsigned short* __restrict__ Wbot0,
                           unsigned short* __restrict__ Wd0,
                           const float* __restrict__ W1, unsigned short* __restrict__ Wbot1,
                           unsigned short* __restrict__ Wd1,
                           const float* __restrict__ Wc0, unsigned short* __restrict__ Wtb0,
                           const float* __restrict__ Wc1, unsigned short* __restrict__ Wtb1,
                           const int* __restrict__ ei0, const int* __restrict__ ei1,
                           int* __restrict__ cnt0, int* __restrict__ cnt1,
                           int* __restrict__ slot0, int* __restrict__ slot1) {
  int b = blockIdx.x;
  int tid = threadIdx.x;
  if (b < 2048) {
    int idx = b * 256 + tid;          // NODE0*16, 8 elems each
    int c8 = idx & 15;
    int r  = idx >> 4;
    int t  = r & (T0 - 1);
    int bn = r >> 7;
    const float* s = data + ((size_t)t * BN + bn) * Ff + c8 * 8;
    float4 a = *(const float4*)s;
    float4 bb = *(const float4*)(s + 4);
    unsigned short o[8];
    o[0] = f2bf(a.x); o[1] = f2bf(a.y); o[2] = f2bf(a.z); o[3] = f2bf(a.w);
    o[4] = f2bf(bb.x); o[5] = f2bf(bb.y); o[6] = f2bf(bb.z); o[7] = f2bf(bb.w);
    *(int4*)(X0b + ((size_t)(bn * T0 + t) * Ff + c8 * 8)) = *(int4*)o;
  } else if (b < 2176) {
    int idx = (b - 2048) * 256 + tid; // 32768 = 256*128
    int n = idx >> 7, k = idx & 127;
    float top = W0[(size_t)k * 256 + n];
    float bot = W0[(size_t)(128 + k) * 256 + n];
    Wbot0[idx] = f2bf(bot);
    Wd0[idx]   = f2bf(top - bot);
  } else if (b < 2432) {
    int idx = (b - 2176) * 256 + tid; // 65536 = 256*256
    int n = idx >> 8, k = idx & 255;
    float top = W1[(size_t)k * 256 + n];
    float bot = W1[(size_t)(256 + k) * 256 + n];
    Wbot1[idx] = f2bf(bot);
    Wd1[idx]   = f2bf(top - bot);
  } else if (b < 3712) {
    int idx = (b - 2432) * 256 + tid; // 5*65536
    int tap = idx >> 16, o = (idx >> 8) & 255, i = idx & 255;
    Wtb0[idx] = f2bf(Wc0[((size_t)o * 256 + i) * 5 + tap]);
  } else if (b < 4992) {
    int idx = (b - 3712) * 256 + tid;
    int tap = idx >> 16, o = (idx >> 8) & 255, i = idx & 255;
    Wtb1[idx] = f2bf(Wc1[((size_t)o * 256 + i) * 5 + tap]);
  } else {
    int e = (b - 4992) * 256 + tid;   // E0+E1 = 393216 over 1536 blocks
    if (e < E0) {
      int d = ei0[E0 + e];
      int p = atomicAdd(&cnt0[d], 1);
      if (p < CAP) slot0[(size_t)d * CAP + p] = ei0[e];
    } else {
      int e2 = e - E0;
      int d = ei1[E1 + e2];
      int p = atomicAdd(&cnt1[d], 1);
      if (p < CAP) slot1[(size_t)d * CAP + p] = ei1[e2];
    }
  }
}

// ---------------- L0 GEMM (v6: reg-resident B, barrier-free k-loop) ----------------
// K=128 compile-time. Insight: A has ZERO intra-block reuse (each wave reads only
// its own 32 rows) and the per-(m16,quad) fragment pattern is 64B-segment coalesced
// directly from global; B (64KB weights) fits in 128 VGPR/lane. So: no LDS staging,
// no k-loop barriers. Two passes (Bm, then P+bias) in one kernel; '#pragma unroll 1'
// keeps the two B register sets from being co-live (~230 VGPR total, 2 waves/EU).
// Epilogue = r4-verified coalesced LDS restage (full 256B line stores).
__global__ __launch_bounds__(256, 2) void k_gemm_rb(const unsigned short* __restrict__ A,
                                                    const unsigned short* __restrict__ Wbot,
                                                    const unsigned short* __restrict__ Wd,
                                                    unsigned short* __restrict__ Bm,
                                                    unsigned short* __restrict__ P,
                                                    const float* __restrict__ bias) {
  __shared__ __align__(16) short E_lds[128 * 136];  // 34.8 KB
  const int ESTR = 136;
  int tid = threadIdx.x;
  int row0 = blockIdx.x * 128;
  int col0 = blockIdx.y * 128;
  int lane = tid & 63, wv = tid >> 6;
  int m16 = lane & 15, quad = lane >> 4;

#pragma unroll 1
  for (int pass = 0; pass < 2; ++pass) {
    const unsigned short* W = pass ? Wd : Wbot;
    // 32 B-fragments/lane: [nt][kf], k-offset kf*32 + quad*8 (kf = kb/32 merged)
    bhalf8 bfr[8][4];
#pragma unroll
    for (int nt = 0; nt < 8; ++nt)
#pragma unroll
      for (int kf = 0; kf < 4; ++kf)
        bfr[nt][kf] = *(const bhalf8*)(W + (size_t)(col0 + nt * 16 + m16) * 128 + kf * 32 + quad * 8);

    floatx4 acc[2][8];
#pragma unroll
    for (int rt = 0; rt < 2; ++rt)
#pragma unroll
      for (int nt = 0; nt < 8; ++nt) acc[rt][nt] = (floatx4){0.f, 0.f, 0.f, 0.f};

#pragma unroll
    for (int kf = 0; kf < 4; ++kf) {
      bhalf8 a0 = *(const bhalf8*)(A + (size_t)(row0 + wv * 32 + m16) * 128 + kf * 32 + quad * 8);
      bhalf8 a1 = *(const bhalf8*)(A + (size_t)(row0 + wv * 32 + 16 + m16) * 128 + kf * 32 + quad * 8);
#pragma unroll
      for (int nt = 0; nt < 8; ++nt) {
        acc[0][nt] = __builtin_amdgcn_mfma_f32_16x16x32_bf16(bfr[nt][kf], a0, acc[0][nt], 0, 0, 0);
        acc[1][nt] = __builtin_amdgcn_mfma_f32_16x16x32_bf16(bfr[nt][kf], a1, acc[1][nt], 0, 0, 0);
      }
    }

    // swapped C/D layout: lane holds node row = row0+wv*32+rt*16+m16,
    // channels col0 + nt*16 + quad*4 + r.
    __syncthreads();   // pass>0: prior stream-out reads done before E overwrite
#pragma unroll
    for (int rt = 0; rt < 2; ++rt) {
      int lr = wv * 32 + rt * 16 + m16;
#pragma unroll
      for (int nt = 0; nt < 8; ++nt) {
        int c = col0 + nt * 16 + quad * 4;
        floatx4 v = acc[rt][nt];
        if (pass) {
          float4 bv = *(const float4*)&bias[c];
          v[0] += bv.x; v[1] += bv.y; v[2] += bv.z; v[3] += bv.w;
        }
        ushort4 o;
        o.x = f2bf(v[0]); o.y = f2bf(v[1]); o.z = f2bf(v[2]); o.w = f2bf(v[3]);
        *(ushort4*)&E_lds[lr * ESTR + nt * 16 + quad * 4] = o;
      }
    }
    __syncthreads();
    unsigned short* Out = pass ? P : Bm;
#pragma unroll
    for (int i = 0; i < 8; ++i) {
      int u = tid + i * 256;           // 2048 chunks = 128 rows x 16
      int r = u >> 4, ch = u & 15;
      int4 v = *(const int4*)&E_lds[r * ESTR + ch * 8];
      *(int4*)(Out + (size_t)(row0 + r) * 256 + col0 + ch * 8) = v;
    }
  }
}

// ---------------- fused dual-output MFMA GEMM (r4 v4, verbatim — used for L1) ----------------
__global__ __launch_bounds__(256) void k_gemm2(const unsigned short* __restrict__ A,
                                               const unsigned short* __restrict__ Wbot,
                                               const unsigned short* __restrict__ Wd,
                                               unsigned short* __restrict__ Bm,
                                               unsigned short* __restrict__ P, int K,
                                               const float* __restrict__ bias) {
  __shared__ __align__(16) short S_lds[3 * 128 * 72];  // 55.3 KB
  short* A_lds  = S_lds;
  short* B0_lds = S_lds + 128 * 72;
  short* B1_lds = S_lds + 2 * 128 * 72;
  short* E_lds  = S_lds;            // epilogue tile: 128 rows x 136 shorts
  int tid = threadIdx.x;
  int row0 = blockIdx.x * 128;
  int col0 = blockIdx.y * 128;
  int lane = tid & 63, wv = tid >> 6;
  int m16 = lane & 15, quad = lane >> 4;
  int sr = tid >> 3, sseg = tid & 7;

  floatx4 accB[2][8], accP[2][8];
#pragma unroll
  for (int rt = 0; rt < 2; ++rt)
#pragma unroll
    for (int nt = 0; nt < 8; ++nt) {
      accB[rt][nt] = (floatx4){0.f, 0.f, 0.f, 0.f};
      accP[rt][nt] = (floatx4){0.f, 0.f, 0.f, 0.f};
    }

  for (int kb = 0; kb < K; kb += 64) {
    __syncthreads();
#pragma unroll
    for (int i = 0; i < 4; ++i) {
      int r = sr + i * 32;
      *(int4*)&A_lds[r * 72 + sseg * 8] =
          *(const int4*)(A + (size_t)(row0 + r) * K + kb + sseg * 8);
      *(int4*)&B0_lds[r * 72 + sseg * 8] =
          *(const int4*)(Wbot + (size_t)(col0 + r) * K + kb + sseg * 8);
      *(int4*)&B1_lds[r * 72 + sseg * 8] =
          *(const int4*)(Wd + (size_t)(col0 + r) * K + kb + sseg * 8);
    }
    __syncthreads();
#pragma unroll
    for (int ks = 0; ks < 2; ++ks) {
      bhalf8 a0 = *(const bhalf8*)&A_lds[(wv * 32 + m16) * 72 + ks * 32 + quad * 8];
      bhalf8 a1 = *(const bhalf8*)&A_lds[(wv * 32 + 16 + m16) * 72 + ks * 32 + quad * 8];
#pragma unroll
      for (int nt = 0; nt < 8; ++nt) {
        bhalf8 b0 = *(const bhalf8*)&B0_lds[(nt * 16 + m16) * 72 + ks * 32 + quad * 8];
        accB[0][nt] = __builtin_amdgcn_mfma_f32_16x16x32_bf16(b0, a0, accB[0][nt], 0, 0, 0);
        accB[1][nt] = __builtin_amdgcn_mfma_f32_16x16x32_bf16(b0, a1, accB[1][nt], 0, 0, 0);
        bhalf8 b1 = *(const bhalf8*)&B1_lds[(nt * 16 + m16) * 72 + ks * 32 + quad * 8];
        accP[0][nt] = __builtin_amdgcn_mfma_f32_16x16x32_bf16(b1, a0, accP[0][nt], 0, 0, 0);
        accP[1][nt] = __builtin_amdgcn_mfma_f32_16x16x32_bf16(b1, a1, accP[1][nt], 0, 0, 0);
      }
    }
  }

  const int ESTR = 136;
  __syncthreads();

  // ---- Bm ----
#pragma unroll
  for (int rt = 0; rt < 2; ++rt) {
    int lr = wv * 32 + rt * 16 + m16;
#pragma unroll
    for (int nt = 0; nt < 8; ++nt) {
      ushort4 ob;
      ob.x = f2bf(accB[rt][nt][0]); ob.y = f2bf(accB[rt][nt][1]);
      ob.z = f2bf(accB[rt][nt][2]); ob.w = f2bf(accB[rt][nt][3]);
      *(ushort4*)&E_lds[lr * ESTR + nt * 16 + quad * 4] = ob;
    }
  }
  __syncthreads();
#pragma unroll
  for (int i = 0; i < 8; ++i) {
    int u = tid + i * 256;           // 2048 chunks = 128 rows x 16
    int r = u >> 4, ch = u & 15;
    int4 v = *(const int4*)&E_lds[r * ESTR + ch * 8];
    *(int4*)(Bm + (size_t)(row0 + r) * 256 + col0 + ch * 8) = v;
  }
  __syncthreads();

  // ---- P (+bias) ----
#pragma unroll
  for (int rt = 0; rt < 2; ++rt) {
    int lr = wv * 32 + rt * 16 + m16;
#pragma unroll
    for (int nt = 0; nt < 8; ++nt) {
      int c = col0 + nt * 16 + quad * 4;
      float4 bv = *(const float4*)&bias[c];
      ushort4 op;
      op.x = f2bf(accP[rt][nt][0] + bv.x); op.y = f2bf(accP[rt][nt][1] + bv.y);
      op.z = f2bf(accP[rt][nt][2] + bv.z); op.w = f2bf(accP[rt][nt][3] + bv.w);
      *(ushort4*)&E_lds[lr * ESTR + nt * 16 + quad * 4] = op;
    }
  }
  __syncthreads();
#pragma unroll
  for (int i = 0; i < 8; ++i) {
    int u = tid + i * 256;
    int r = u >> 4, ch = u & 15;
    int4 v = *(const int4*)&E_lds[r * ESTR + ch * 8];
    *(int4*)(P + (size_t)(row0 + r) * 256 + col0 + ch * 8) = v;
  }
}

// ---------------- segment max + fused relu epilogue (v2, kept) ----------------
__global__ __launch_bounds__(256) void k_maxg2(const unsigned short* __restrict__ Bm,
                                               const int* __restrict__ cnt,
                                               const int* __restrict__ slot,
                                               const unsigned short* __restrict__ P,
                                               unsigned short* __restrict__ X1) {
  int node = blockIdx.x * 4 + (threadIdx.x >> 6);
  int lane = threadIdx.x & 63;
  int half = lane >> 5, c8 = lane & 31;
  int n = cnt[node];
  if (n > CAP) n = CAP;
  const int* sl = slot + (size_t)node * CAP;
  float m[8];
#pragma unroll
  for (int e = 0; e < 8; ++e) m[e] = -INFINITY;
  for (int i = 0; i < n; i += 8) {
    int s[4];
#pragma unroll
    for (int j = 0; j < 4; ++j) {
      int idx = i + 2 * j + half;
      s[j] = sl[(idx < n) ? idx : (n - 1)];
    }
    int4 v[4];
#pragma unroll
    for (int j = 0; j < 4; ++j)
      v[j] = *(const int4*)(Bm + (size_t)s[j] * 256 + c8 * 8);
#pragma unroll
    for (int j = 0; j < 4; ++j) {
      max2(m[0], m[1], v[j].x);
      max2(m[2], m[3], v[j].y);
      max2(m[4], m[5], v[j].z);
      max2(m[6], m[7], v[j].w);
    }
  }
#pragma unroll
  for (int e = 0; e < 8; ++e) m[e] = fmaxf(m[e], __shfl_xor(m[e], 32));
  if (half == 0) {
    int4 p = *(const int4*)(P + (size_t)node * 256 + c8 * 8);
    int4 o;
    unsigned short r0, r1;
    r0 = f2bf(fmaxf(bf2f((unsigned short)(p.x & 0xffff)) + m[0], 0.f));
    r1 = f2bf(fmaxf(bf2f((unsigned short)((unsigned)p.x >> 16)) + m[1], 0.f));
    o.x = (int)r0 | ((int)r1 << 16);
    r0 = f2bf(fmaxf(bf2f((unsigned short)(p.y & 0xffff)) + m[2], 0.f));
    r1 = f2bf(fmaxf(bf2f((unsigned short)((unsigned)p.y >> 16)) + m[3], 0.f));
    o.y = (int)r0 | ((int)r1 << 16);
    r0 = f2bf(fmaxf(bf2f((unsigned short)(p.z & 0xffff)) + m[4], 0.f));
    r1 = f2bf(fmaxf(bf2f((unsigned short)((unsigned)p.z >> 16)) + m[5], 0.f));
    o.z = (int)r0 | ((int)r1 << 16);
    r0 = f2bf(fmaxf(bf2f((unsigned short)(p.w & 0xffff)) + m[6], 0.f));
    r1 = f2bf(fmaxf(bf2f((unsigned short)((unsigned)p.w >> 16)) + m[7], 0.f));
    o.w = (int)r0 | ((int)r1 << 16);
    *(int4*)(X1 + (size_t)node * 256 + c8 * 8) = o;
  }
}

// ---------------- MFMA temporal conv (r4 direct staging) ----------------
// L0 runs NT=2 (512 blocks = 2/CU). L1 now runs NT=1: at NT=2 its grid is only
// 256 blocks = 1 block/CU (exposed barriers, r5 lesson); NT=1 doubles the grid
// to 512 = 2/CU at 36.5KB LDS.
template <int TRows, int NT, bool OUT_F32>
__global__ __launch_bounds__(256) void k_conv32(const unsigned short* __restrict__ X,
                                                const unsigned short* __restrict__ Wtb,
                                                const float* __restrict__ bc,
                                                void* __restrict__ Yout) {
  const int CB = NT * 64;                        // block cols
  __shared__ __align__(16) short A_lds[2 * 68 * 40];   // [win][row 0..67][k32 + pad8]
  __shared__ __align__(16) short B_lds[5 * CB * 40];   // [tap*CB + col][k32 + pad8]
  int tid = threadIdx.x;
  int row0 = blockIdx.x * 128;
  int col0 = blockIdx.y * CB;
  int lane = tid & 63, wv = tid >> 6;
  int l31 = lane & 31, khalf = lane >> 5;
  int h = wv & 1, cpart = wv >> 1;

  floatx16 acc[2][NT];
#pragma unroll
  for (int rt = 0; rt < 2; ++rt)
#pragma unroll
    for (int ct = 0; ct < NT; ++ct)
#pragma unroll
      for (int r = 0; r < 16; ++r) acc[rt][ct][r] = 0.f;

  for (int kb = 0; kb < 256; kb += 32) {
    __syncthreads();
    // stage A: two 68-row halo windows (rows base-2 .. base+66), zero outside bn
    for (int u = tid; u < 544; u += 256) {
      int s = (u >= 272) ? 1 : 0;
      int v = u - s * 272;
      int rr = v >> 2, seg = v & 3;
      int base = row0 + s * 64;
      int lo = base & ~(TRows - 1);
      int gr = base + rr - 2;
      int4 val = {0, 0, 0, 0};
      if (gr >= lo && gr < lo + TRows)
        val = *(const int4*)(X + (size_t)gr * 256 + kb + seg * 8);
      *(int4*)&A_lds[(s * 68 + rr) * 40 + seg * 8] = val;
    }
    // stage B: 5 taps x CB cols x 32 k
#pragma unroll
    for (int i = 0; i < 5 * NT; ++i) {
      int u = tid + i * 256;            // 5*CB rows x 4 segs
      int r = u >> 2, seg = u & 3;      // r = tap*CB + col
      int tap = r / CB, col = r % CB;
      *(int4*)&B_lds[r * 40 + seg * 8] =
          *(const int4*)(Wtb + (size_t)tap * 65536 + (size_t)(col0 + col) * 256 + kb + seg * 8);
    }
    __syncthreads();
#pragma unroll
    for (int tap = 0; tap < 5; ++tap) {
#pragma unroll
      for (int ks = 0; ks < 2; ++ks) {
        int ko = ks * 16 + khalf * 8;
        bhalf8 a[2];
#pragma unroll
        for (int rt = 0; rt < 2; ++rt)
          a[rt] = *(const bhalf8*)&A_lds[(h * 68 + rt * 32 + l31 + tap) * 40 + ko];
#pragma unroll
        for (int ct = 0; ct < NT; ++ct) {
          bhalf8 b = *(const bhalf8*)&B_lds[(tap * CB + cpart * NT * 32 + ct * 32 + l31) * 40 + ko];
#pragma unroll
          for (int rt = 0; rt < 2; ++rt)
            acc[rt][ct] = __builtin_amdgcn_mfma_f32_32x32x16_bf16(a[rt], b, acc[rt][ct], 0, 0, 0);
        }
      }
    }
  }

#pragma unroll
  for (int rt = 0; rt < 2; ++rt) {
#pragma unroll
    for (int ct = 0; ct < NT; ++ct) {
      int c = col0 + cpart * NT * 32 + ct * 32 + l31;
      float bv = bc[c];
#pragma unroll
      for (int r = 0; r < 16; r += 2) {
        int rowg = row0 + h * 64 + rt * 32 + 4 * khalf + 8 * (r >> 2) + (r & 3);
        float y0 = fmaxf(acc[rt][ct][r] + bv, 0.f);
        float y1 = fmaxf(acc[rt][ct][r + 1] + bv, 0.f);
        float p = fmaxf(y0, y1);
        int o = rowg >> 1;
        if (OUT_F32) ((float*)Yout)[(size_t)o * 256 + c] = p;
        else ((unsigned short*)Yout)[(size_t)o * 256 + c] = f2bf(p);
      }
    }
  }
}

extern "C" void kernel_launch(void* const* d_in, const int* in_sizes, int n_in,
                              void* d_out, int out_size, void* d_ws, size_t ws_size,
                              hipStream_t stream) {
  const float* data = (const float*)d_in[0];
  const int* ei0 = (const int*)d_in[2];
  const int* ei1 = (const int*)d_in[3];
  const float* W0  = (const float*)d_in[4];
  const float* b0  = (const float*)d_in[5];
  const float* Wc0 = (const float*)d_in[6];
  const float* bc0 = (const float*)d_in[7];
  const float* W1  = (const float*)d_in[8];
  const float* b1  = (const float*)d_in[9];
  const float* Wc1 = (const float*)d_in[10];
  const float* bc1 = (const float*)d_in[11];
  float* out = (float*)d_out;

  char* base = (char*)d_ws;
  size_t off = 0;
  auto alloc = [&](size_t bytes) { void* p = base + off; off += (bytes + 255) & ~(size_t)255; return p; };
  unsigned short* X0b   = (unsigned short*)alloc((size_t)NODE0 * Ff * 2);
  unsigned short* Bm    = (unsigned short*)alloc((size_t)NODE0 * Hh * 2);
  unsigned short* P     = (unsigned short*)alloc((size_t)NODE0 * Hh * 2);
  unsigned short* X1b   = (unsigned short*)alloc((size_t)NODE0 * Hh * 2);
  unsigned short* Y0b   = (unsigned short*)alloc((size_t)NODE1 * Hh * 2);
  unsigned short* Wbot0 = (unsigned short*)alloc(256 * 128 * 2);
  unsigned short* Wd0   = (unsigned short*)alloc(256 * 128 * 2);
  unsigned short* Wbot1 = (unsigned short*)alloc(256 * 256 * 2);
  unsigned short* Wd1   = (unsigned short*)alloc(256 * 256 * 2);
  unsigned short* Wtb0  = (unsigned short*)alloc(5 * 65536 * 2);
  unsigned short* Wtb1  = (unsigned short*)alloc(5 * 65536 * 2);
  int* cnt0  = (int*)alloc(NODE0 * 4);      // cnt0+cnt1 adjacent: one memset
  int* cnt1  = (int*)alloc(NODE1 * 4);
  int* slot0 = (int*)alloc((size_t)NODE0 * CAP * 4);
  int* slot1 = (int*)alloc((size_t)NODE1 * CAP * 4);

  hipMemsetAsync(cnt0, 0, (NODE0 + NODE1) * sizeof(int), stream);

  k_prepfill<<<6528, 256, 0, stream>>>(data, X0b, W0, Wbot0, Wd0, W1, Wbot1, Wd1,
                                       Wc0, Wtb0, Wc1, Wtb1,
                                       ei0, ei1, cnt0, cnt1, slot0, slot1);

  // ---- layer 0 ----
  k_gemm_rb<<<dim3(NODE0 / 128, 2), 256, 0, stream>>>(X0b, Wbot0, Wd0, Bm, P, b0);
  k_maxg2<<<NODE0 / 4, 256, 0, stream>>>(Bm, cnt0, slot0, P, X1b);
  k_conv32<128, 2, false><<<dim3(NODE0 / 128, 2), 256, 0, stream>>>(X1b, Wtb0, bc0, Y0b);

  // ---- layer 1 ----
  k_gemm2<<<dim3(NODE1 / 128, 2), 256, 0, stream>>>(Y0b, Wbot1, Wd1, Bm, P, 256, b1);
  k_maxg2<<<NODE1 / 4, 256, 0, stream>>>(Bm, cnt1, slot1, P, X1b);
  k_conv32<64, 1, true><<<dim3(NODE1 / 128, 4), 256, 0, stream>>>(X1b, Wtb1, bc1, out);
}

// Round 8
// 220.727 us; speedup vs baseline: 1.0886x; 1.0292x over previous
//
#include <hip/hip_runtime.h>
#include <hip/hip_bf16.h>
#include <math.h>

#define T0 128
#define BN 256           // B*N = 8*32
#define Ff 128
#define Hh 256
#define NODE0 32768      // BN*T0
#define E0 262144        // NODE0*8
#define T1 64
#define NODE1 16384      // BN*T1
#define E1 131072
#define CAP 48           // per-node in-edge capacity; deg ~ Poisson(8), P(>48) ~ 1e-25

typedef __attribute__((ext_vector_type(8))) short bhalf8;
typedef __attribute__((ext_vector_type(4))) float floatx4;
typedef __attribute__((ext_vector_type(16))) float floatx16;

__device__ __forceinline__ unsigned short f2bf(float x) {
  union { float f; unsigned u; } v; v.f = x;
  unsigned r = v.u + 0x7fff + ((v.u >> 16) & 1);
  return (unsigned short)(r >> 16);
}
__device__ __forceinline__ float bf2f(unsigned short b) {
  union { unsigned u; float f; } v; v.u = ((unsigned)b) << 16;
  return v.f;
}
// update two running maxes from one packed int (2 bf16)
__device__ __forceinline__ void max2(float& mlo, float& mhi, int p) {
  union { unsigned u; float f; } lo, hi;
  lo.u = ((unsigned)p) << 16;
  hi.u = ((unsigned)p) & 0xffff0000u;
  mlo = fmaxf(mlo, lo.f);
  mhi = fmaxf(mhi, hi.f);
}

// ---------------- fused prep + edge-fill kernel ----------------
__global__ void k_prepfill(const float* __restrict__ data, unsigned short* __restrict__ X0b,
                           const float* __restrict__ W0, unsigned short* __restrict__ Wbot0,
                           unsigned short* __restrict__ Wd0,
                           const float* __restrict__ W1, unsigned short* __restrict__ Wbot1,
                           unsigned short* __restrict__ Wd1,
                           const float* __restrict__ Wc0, unsigned short* __restrict__ Wtb0,
                           const float* __restrict__ Wc1, unsigned short* __restrict__ Wtb1,
                           const int* __restrict__ ei0, const int* __restrict__ ei1,
                           int* __restrict__ cnt0, int* __restrict__ cnt1,
                           int* __restrict__ slot0, int* __restrict__ slot1) {
  int b = blockIdx.x;
  int tid = threadIdx.x;
  if (b < 2048) {
    int idx = b * 256 + tid;          // NODE0*16, 8 elems each
    int c8 = idx & 15;
    int r  = idx >> 4;
    int t  = r & (T0 - 1);
    int bn = r >> 7;
    const float* s = data + ((size_t)t * BN + bn) * Ff + c8 * 8;
    float4 a = *(const float4*)s;
    float4 bb = *(const float4*)(s + 4);
    unsigned short o[8];
    o[0] = f2bf(a.x); o[1] = f2bf(a.y); o[2] = f2bf(a.z); o[3] = f2bf(a.w);
    o[4] = f2bf(bb.x); o[5] = f2bf(bb.y); o[6] = f2bf(bb.z); o[7] = f2bf(bb.w);
    *(int4*)(X0b + ((size_t)(bn * T0 + t) * Ff + c8 * 8)) = *(int4*)o;
  } else if (b < 2176) {
    int idx = (b - 2048) * 256 + tid; // 32768 = 256*128
    int n = idx >> 7, k = idx & 127;
    float top = W0[(size_t)k * 256 + n];
    float bot = W0[(size_t)(128 + k) * 256 + n];
    Wbot0[idx] = f2bf(bot);
    Wd0[idx]   = f2bf(top - bot);
  } else if (b < 2432) {
    int idx = (b - 2176) * 256 + tid; // 65536 = 256*256
    int n = idx >> 8, k = idx & 255;
    float top = W1[(size_t)k * 256 + n];
    float bot = W1[(size_t)(256 + k) * 256 + n];
    Wbot1[idx] = f2bf(bot);
    Wd1[idx]   = f2bf(top - bot);
  } else if (b < 3712) {
    int idx = (b - 2432) * 256 + tid; // 5*65536
    int tap = idx >> 16, o = (idx >> 8) & 255, i = idx & 255;
    Wtb0[idx] = f2bf(Wc0[((size_t)o * 256 + i) * 5 + tap]);
  } else if (b < 4992) {
    int idx = (b - 3712) * 256 + tid;
    int tap = idx >> 16, o = (idx >> 8) & 255, i = idx & 255;
    Wtb1[idx] = f2bf(Wc1[((size_t)o * 256 + i) * 5 + tap]);
  } else {
    int e = (b - 4992) * 256 + tid;   // E0+E1 = 393216 over 1536 blocks
    if (e < E0) {
      int d = ei0[E0 + e];
      int p = atomicAdd(&cnt0[d], 1);
      if (p < CAP) slot0[(size_t)d * CAP + p] = ei0[e];
    } else {
      int e2 = e - E0;
      int d = ei1[E1 + e2];
      int p = atomicAdd(&cnt1[d], 1);
      if (p < CAP) slot1[(size_t)d * CAP + p] = ei1[e2];
    }
  }
}

// ---------------- fused dual-output MFMA GEMM (v4.1: merged single-pass epilogue) ----------------
// r4 structure (verified 219.2us total). Change vs r4: BOTH output tiles (Bm and
// P+bias) staged in LDS at once (69.6KB union; still 2 blocks/CU) -> ONE barrier
// pair instead of two, and the stream-out interleaves Bm/P stores for 2x MLP in
// the store tail.
__global__ __launch_bounds__(256) void k_gemm2(const unsigned short* __restrict__ A,
                                               const unsigned short* __restrict__ Wbot,
                                               const unsigned short* __restrict__ Wd,
                                               unsigned short* __restrict__ Bm,
                                               unsigned short* __restrict__ P, int K,
                                               const float* __restrict__ bias) {
  __shared__ __align__(16) short S_lds[2 * 128 * 136];  // 69.6 KB (staging 55.3KB / 2 epi tiles)
  short* A_lds  = S_lds;
  short* B0_lds = S_lds + 128 * 72;
  short* B1_lds = S_lds + 2 * 128 * 72;
  short* E0_lds = S_lds;              // Bm tile: 128 x 136 shorts
  short* E1_lds = S_lds + 128 * 136;  // P tile
  const int ESTR = 136;
  int tid = threadIdx.x;
  int row0 = blockIdx.x * 128;
  int col0 = blockIdx.y * 128;
  int lane = tid & 63, wv = tid >> 6;
  int m16 = lane & 15, quad = lane >> 4;
  int sr = tid >> 3, sseg = tid & 7;

  floatx4 accB[2][8], accP[2][8];
#pragma unroll
  for (int rt = 0; rt < 2; ++rt)
#pragma unroll
    for (int nt = 0; nt < 8; ++nt) {
      accB[rt][nt] = (floatx4){0.f, 0.f, 0.f, 0.f};
      accP[rt][nt] = (floatx4){0.f, 0.f, 0.f, 0.f};
    }

  for (int kb = 0; kb < K; kb += 64) {
    __syncthreads();
#pragma unroll
    for (int i = 0; i < 4; ++i) {
      int r = sr + i * 32;
      *(int4*)&A_lds[r * 72 + sseg * 8] =
          *(const int4*)(A + (size_t)(row0 + r) * K + kb + sseg * 8);
      *(int4*)&B0_lds[r * 72 + sseg * 8] =
          *(const int4*)(Wbot + (size_t)(col0 + r) * K + kb + sseg * 8);
      *(int4*)&B1_lds[r * 72 + sseg * 8] =
          *(const int4*)(Wd + (size_t)(col0 + r) * K + kb + sseg * 8);
    }
    __syncthreads();
#pragma unroll
    for (int ks = 0; ks < 2; ++ks) {
      bhalf8 a0 = *(const bhalf8*)&A_lds[(wv * 32 + m16) * 72 + ks * 32 + quad * 8];
      bhalf8 a1 = *(const bhalf8*)&A_lds[(wv * 32 + 16 + m16) * 72 + ks * 32 + quad * 8];
#pragma unroll
      for (int nt = 0; nt < 8; ++nt) {
        bhalf8 b0 = *(const bhalf8*)&B0_lds[(nt * 16 + m16) * 72 + ks * 32 + quad * 8];
        accB[0][nt] = __builtin_amdgcn_mfma_f32_16x16x32_bf16(b0, a0, accB[0][nt], 0, 0, 0);
        accB[1][nt] = __builtin_amdgcn_mfma_f32_16x16x32_bf16(b0, a1, accB[1][nt], 0, 0, 0);
        bhalf8 b1 = *(const bhalf8*)&B1_lds[(nt * 16 + m16) * 72 + ks * 32 + quad * 8];
        accP[0][nt] = __builtin_amdgcn_mfma_f32_16x16x32_bf16(b1, a0, accP[0][nt], 0, 0, 0);
        accP[1][nt] = __builtin_amdgcn_mfma_f32_16x16x32_bf16(b1, a1, accP[1][nt], 0, 0, 0);
      }
    }
  }

  // swapped C/D layout: lane holds node row = row0+wv*32+rt*16+m16,
  // channels col0 + nt*16 + quad*4 + r.
  __syncthreads();   // all waves done reading staging LDS before overwrite
#pragma unroll
  for (int rt = 0; rt < 2; ++rt) {
    int lr = wv * 32 + rt * 16 + m16;
#pragma unroll
    for (int nt = 0; nt < 8; ++nt) {
      int c = col0 + nt * 16 + quad * 4;
      float4 bv = *(const float4*)&bias[c];
      ushort4 ob, op;
      ob.x = f2bf(accB[rt][nt][0]); ob.y = f2bf(accB[rt][nt][1]);
      ob.z = f2bf(accB[rt][nt][2]); ob.w = f2bf(accB[rt][nt][3]);
      op.x = f2bf(accP[rt][nt][0] + bv.x); op.y = f2bf(accP[rt][nt][1] + bv.y);
      op.z = f2bf(accP[rt][nt][2] + bv.z); op.w = f2bf(accP[rt][nt][3] + bv.w);
      *(ushort4*)&E0_lds[lr * ESTR + nt * 16 + quad * 4] = ob;
      *(ushort4*)&E1_lds[lr * ESTR + nt * 16 + quad * 4] = op;
    }
  }
  __syncthreads();
#pragma unroll
  for (int i = 0; i < 8; ++i) {
    int u = tid + i * 256;           // 2048 chunks = 128 rows x 16
    int r = u >> 4, ch = u & 15;
    int4 vb = *(const int4*)&E0_lds[r * ESTR + ch * 8];
    int4 vp = *(const int4*)&E1_lds[r * ESTR + ch * 8];
    *(int4*)(Bm + (size_t)(row0 + r) * 256 + col0 + ch * 8) = vb;
    *(int4*)(P  + (size_t)(row0 + r) * 256 + col0 + ch * 8) = vp;
  }
}

// ---------------- segment max + fused relu epilogue (v2, kept) ----------------
__global__ __launch_bounds__(256) void k_maxg2(const unsigned short* __restrict__ Bm,
                                               const int* __restrict__ cnt,
                                               const int* __restrict__ slot,
                                               const unsigned short* __restrict__ P,
                                               unsigned short* __restrict__ X1) {
  int node = blockIdx.x * 4 + (threadIdx.x >> 6);
  int lane = threadIdx.x & 63;
  int half = lane >> 5, c8 = lane & 31;
  int n = cnt[node];
  if (n > CAP) n = CAP;
  const int* sl = slot + (size_t)node * CAP;
  float m[8];
#pragma unroll
  for (int e = 0; e < 8; ++e) m[e] = -INFINITY;
  for (int i = 0; i < n; i += 8) {
    int s[4];
#pragma unroll
    for (int j = 0; j < 4; ++j) {
      int idx = i + 2 * j + half;
      s[j] = sl[(idx < n) ? idx : (n - 1)];
    }
    int4 v[4];
#pragma unroll
    for (int j = 0; j < 4; ++j)
      v[j] = *(const int4*)(Bm + (size_t)s[j] * 256 + c8 * 8);
#pragma unroll
    for (int j = 0; j < 4; ++j) {
      max2(m[0], m[1], v[j].x);
      max2(m[2], m[3], v[j].y);
      max2(m[4], m[5], v[j].z);
      max2(m[6], m[7], v[j].w);
    }
  }
#pragma unroll
  for (int e = 0; e < 8; ++e) m[e] = fmaxf(m[e], __shfl_xor(m[e], 32));
  if (half == 0) {
    int4 p = *(const int4*)(P + (size_t)node * 256 + c8 * 8);
    int4 o;
    unsigned short r0, r1;
    r0 = f2bf(fmaxf(bf2f((unsigned short)(p.x & 0xffff)) + m[0], 0.f));
    r1 = f2bf(fmaxf(bf2f((unsigned short)((unsigned)p.x >> 16)) + m[1], 0.f));
    o.x = (int)r0 | ((int)r1 << 16);
    r0 = f2bf(fmaxf(bf2f((unsigned short)(p.y & 0xffff)) + m[2], 0.f));
    r1 = f2bf(fmaxf(bf2f((unsigned short)((unsigned)p.y >> 16)) + m[3], 0.f));
    o.y = (int)r0 | ((int)r1 << 16);
    r0 = f2bf(fmaxf(bf2f((unsigned short)(p.z & 0xffff)) + m[4], 0.f));
    r1 = f2bf(fmaxf(bf2f((unsigned short)((unsigned)p.z >> 16)) + m[5], 0.f));
    o.z = (int)r0 | ((int)r1 << 16);
    r0 = f2bf(fmaxf(bf2f((unsigned short)(p.w & 0xffff)) + m[6], 0.f));
    r1 = f2bf(fmaxf(bf2f((unsigned short)((unsigned)p.w >> 16)) + m[7], 0.f));
    o.w = (int)r0 | ((int)r1 << 16);
    *(int4*)(X1 + (size_t)node * 256 + c8 * 8) = o;
  }
}

// ---------------- MFMA temporal conv (r4 direct staging, NT=2 both layers) ----------------
template <int TRows, int NT, bool OUT_F32>
__global__ __launch_bounds__(256) void k_conv32(const unsigned short* __restrict__ X,
                                                const unsigned short* __restrict__ Wtb,
                                                const float* __restrict__ bc,
                                                void* __restrict__ Yout) {
  const int CB = NT * 64;                        // block cols
  __shared__ __align__(16) short A_lds[2 * 68 * 40];   // [win][row 0..67][k32 + pad8]
  __shared__ __align__(16) short B_lds[5 * CB * 40];   // [tap*CB + col][k32 + pad8]
  int tid = threadIdx.x;
  int row0 = blockIdx.x * 128;
  int col0 = blockIdx.y * CB;
  int lane = tid & 63, wv = tid >> 6;
  int l31 = lane & 31, khalf = lane >> 5;
  int h = wv & 1, cpart = wv >> 1;

  floatx16 acc[2][NT];
#pragma unroll
  for (int rt = 0; rt < 2; ++rt)
#pragma unroll
    for (int ct = 0; ct < NT; ++ct)
#pragma unroll
      for (int r = 0; r < 16; ++r) acc[rt][ct][r] = 0.f;

  for (int kb = 0; kb < 256; kb += 32) {
    __syncthreads();
    // stage A: two 68-row halo windows (rows base-2 .. base+66), zero outside bn
    for (int u = tid; u < 544; u += 256) {
      int s = (u >= 272) ? 1 : 0;
      int v = u - s * 272;
      int rr = v >> 2, seg = v & 3;
      int base = row0 + s * 64;
      int lo = base & ~(TRows - 1);
      int gr = base + rr - 2;
      int4 val = {0, 0, 0, 0};
      if (gr >= lo && gr < lo + TRows)
        val = *(const int4*)(X + (size_t)gr * 256 + kb + seg * 8);
      *(int4*)&A_lds[(s * 68 + rr) * 40 + seg * 8] = val;
    }
    // stage B: 5 taps x CB cols x 32 k
#pragma unroll
    for (int i = 0; i < 5 * NT; ++i) {
      int u = tid + i * 256;            // 5*CB rows x 4 segs
      int r = u >> 2, seg = u & 3;      // r = tap*CB + col
      int tap = r / CB, col = r % CB;
      *(int4*)&B_lds[r * 40 + seg * 8] =
          *(const int4*)(Wtb + (size_t)tap * 65536 + (size_t)(col0 + col) * 256 + kb + seg * 8);
    }
    __syncthreads();
#pragma unroll
    for (int tap = 0; tap < 5; ++tap) {
#pragma unroll
      for (int ks = 0; ks < 2; ++ks) {
        int ko = ks * 16 + khalf * 8;
        bhalf8 a[2];
#pragma unroll
        for (int rt = 0; rt < 2; ++rt)
          a[rt] = *(const bhalf8*)&A_lds[(h * 68 + rt * 32 + l31 + tap) * 40 + ko];
#pragma unroll
        for (int ct = 0; ct < NT; ++ct) {
          bhalf8 b = *(const bhalf8*)&B_lds[(tap * CB + cpart * NT * 32 + ct * 32 + l31) * 40 + ko];
#pragma unroll
          for (int rt = 0; rt < 2; ++rt)
            acc[rt][ct] = __builtin_amdgcn_mfma_f32_32x32x16_bf16(a[rt], b, acc[rt][ct], 0, 0, 0);
        }
      }
    }
  }

#pragma unroll
  for (int rt = 0; rt < 2; ++rt) {
#pragma unroll
    for (int ct = 0; ct < NT; ++ct) {
      int c = col0 + cpart * NT * 32 + ct * 32 + l31;
      float bv = bc[c];
#pragma unroll
      for (int r = 0; r < 16; r += 2) {
        int rowg = row0 + h * 64 + rt * 32 + 4 * khalf + 8 * (r >> 2) + (r & 3);
        float y0 = fmaxf(acc[rt][ct][r] + bv, 0.f);
        float y1 = fmaxf(acc[rt][ct][r + 1] + bv, 0.f);
        float p = fmaxf(y0, y1);
        int o = rowg >> 1;
        if (OUT_F32) ((float*)Yout)[(size_t)o * 256 + c] = p;
        else ((unsigned short*)Yout)[(size_t)o * 256 + c] = f2bf(p);
      }
    }
  }
}

extern "C" void kernel_launch(void* const* d_in, const int* in_sizes, int n_in,
                              void* d_out, int out_size, void* d_ws, size_t ws_size,
                              hipStream_t stream) {
  const float* data = (const float*)d_in[0];
  const int* ei0 = (const int*)d_in[2];
  const int* ei1 = (const int*)d_in[3];
  const float* W0  = (const float*)d_in[4];
  const float* b0  = (const float*)d_in[5];
  const float* Wc0 = (const float*)d_in[6];
  const float* bc0 = (const float*)d_in[7];
  const float* W1  = (const float*)d_in[8];
  const float* b1  = (const float*)d_in[9];
  const float* Wc1 = (const float*)d_in[10];
  const float* bc1 = (const float*)d_in[11];
  float* out = (float*)d_out;

  char* base = (char*)d_ws;
  size_t off = 0;
  auto alloc = [&](size_t bytes) { void* p = base + off; off += (bytes + 255) & ~(size_t)255; return p; };
  unsigned short* X0b   = (unsigned short*)alloc((size_t)NODE0 * Ff * 2);
  unsigned short* Bm    = (unsigned short*)alloc((size_t)NODE0 * Hh * 2);
  unsigned short* P     = (unsigned short*)alloc((size_t)NODE0 * Hh * 2);
  unsigned short* X1b   = (unsigned short*)alloc((size_t)NODE0 * Hh * 2);
  unsigned short* Y0b   = (unsigned short*)alloc((size_t)NODE1 * Hh * 2);
  unsigned short* Wbot0 = (unsigned short*)alloc(256 * 128 * 2);
  unsigned short* Wd0   = (unsigned short*)alloc(256 * 128 * 2);
  unsigned short* Wbot1 = (unsigned short*)alloc(256 * 256 * 2);
  unsigned short* Wd1   = (unsigned short*)alloc(256 * 256 * 2);
  unsigned short* Wtb0  = (unsigned short*)alloc(5 * 65536 * 2);
  unsigned short* Wtb1  = (unsigned short*)alloc(5 * 65536 * 2);
  int* cnt0  = (int*)alloc(NODE0 * 4);      // cnt0+cnt1 adjacent: one memset
  int* cnt1  = (int*)alloc(NODE1 * 4);
  int* slot0 = (int*)alloc((size_t)NODE0 * CAP * 4);
  int* slot1 = (int*)alloc((size_t)NODE1 * CAP * 4);

  hipMemsetAsync(cnt0, 0, (NODE0 + NODE1) * sizeof(int), stream);

  k_prepfill<<<6528, 256, 0, stream>>>(data, X0b, W0, Wbot0, Wd0, W1, Wbot1, Wd1,
                                       Wc0, Wtb0, Wc1, Wtb1,
                                       ei0, ei1, cnt0, cnt1, slot0, slot1);

  // ---- layer 0 ----
  k_gemm2<<<dim3(NODE0 / 128, 2), 256, 0, stream>>>(X0b, Wbot0, Wd0, Bm, P, 128, b0);
  k_maxg2<<<NODE0 / 4, 256, 0, stream>>>(Bm, cnt0, slot0, P, X1b);
  k_conv32<128, 2, false><<<dim3(NODE0 / 128, 2), 256, 0, stream>>>(X1b, Wtb0, bc0, Y0b);

  // ---- layer 1 ----
  k_gemm2<<<dim3(NODE1 / 128, 2), 256, 0, stream>>>(Y0b, Wbot1, Wd1, Bm, P, 256, b1);
  k_maxg2<<<NODE1 / 4, 256, 0, stream>>>(Bm, cnt1, slot1, P, X1b);
  k_conv32<64, 2, true><<<dim3(NODE1 / 128, 2), 256, 0, stream>>>(X1b, Wtb1, bc1, out);
}